// Round 8
// baseline (147.173 us; speedup 1.0000x reference)
//
#include <hip/hip_runtime.h>

#define HW    262144      // 512*512
#define BNUM  4
#define NC    33          // labels 0..32
#define NI    32          // instance channels

#define NB     1024       // t-space bins
#define BSCALE 64.0f      // NB / TMAX (TMAX = 16)
#define EG     4096       // e-grid bins in scan
#define ESCALE 2048.0f    // EG / 2.0

typedef unsigned long long ull;

// ws layout in 32-bit words:
//   [0 .. 8192)    t-hist: u64[NB] per sample (zeroed in-kernel pre-sync)
//   [8192..8196)   cntA[s]  phase-A arrival counters   (zeroed by init)
//   [8196..8200)   crdy[s]  cons-ready flags           (zeroed by init)
//   [8200..8204)   cntB[s]  phase-B arrival counters   (zeroed by init)
//   [8204]         cntF     finalize counter           (zeroed by init)
//   [8208..8212)   fin[s]   per-sample losses
//   [8212..8216)   vart[s]  pooled variance term
//   [8216..8744)   cons float4[s][NC]
//   [8744.. )      partials float[s][64][168]
#define W_CNTA 8192
#define W_CRDY 8196
#define W_CNTB 8200
#define W_CNTF 8204
#define W_FINL 8208
#define W_VART 8212
#define W_CONS 8216
#define W_PART 8744
#define PJ 168            // padded words per partial slot (165 used)
#define PS (64 * PJ)      // words per sample

// ---------------- K0: zero the sync counters (16 words, 1 wave).
__global__ void __launch_bounds__(64) init_kernel(float* __restrict__ ws) {
  unsigned* wsu = (unsigned*)ws;
  int t = threadIdx.x;
  if (t < 16) wsu[W_CNTA + t] = 0u;   // cntA[4], crdy[4], cntB[4], cntF(+pad)
}

// ---------------- Fused: stats -> (last block: cons+vart) -> spin ->
// hist -> u64 flush -> (last block: scan). One global read of inputs.
// Grid = 256 blocks = #CUs, 8 waves, ~41 KB LDS: all blocks co-resident,
// so the per-sample producer-consumer spin cannot deadlock.
__global__ void __launch_bounds__(512) fused_kernel(
    const float* __restrict__ emb, const float* __restrict__ sig,
    const int* __restrict__ gt, float* __restrict__ ws,
    float* __restrict__ out) {
  int s  = blockIdx.y;
  int lb = blockIdx.x;           // 0..63
  int t = threadIdx.x;
  int lane = t & 63, wid = t >> 6;
  __shared__ float acc[8][165];       // phase-A per-wave accumulators
  __shared__ unsigned hist[NB * 8];   // 32 KB; aliased as e-grid in tail
  __shared__ float sums2[2][165];
  __shared__ float sums[165];
  __shared__ float4 consS[NC];
  __shared__ ull wsum[8];
  __shared__ float red[8];
  __shared__ int isred, flag;
  unsigned* wsu = (unsigned*)ws;

  const float* e0p = emb + (size_t)s * 2 * HW;
  const float* e1p = e0p + HW;
  const float* sp  = sig + (size_t)s * HW;
  const int*   gp  = gt  + (size_t)s * HW;
  // prefetch 8 px/thread: loads issued before LDS init; registers carried
  // through the cons sync so phase B never re-reads global memory.
  int base = lb * 4096 + t * 4;
  int4   lbl0 = *(const int4*)(gp + base);
  int4   lbl1 = *(const int4*)(gp + base + 2048);
  float4 px0  = *(const float4*)(e0p + base);
  float4 px1  = *(const float4*)(e0p + base + 2048);
  float4 py0  = *(const float4*)(e1p + base);
  float4 py1  = *(const float4*)(e1p + base + 2048);
  float4 sg0  = *(const float4*)(sp + base);
  float4 sg1  = *(const float4*)(sp + base + 2048);
  // zero this block's slice of the global t-hist (32 words each, covers
  // all 8192 words; ordered before any phase-B atomic via the cons sync)
  if (t < 32) wsu[(s * 64 + lb) * 32 + t] = 0u;
  for (int k = t; k < 8 * 165; k += 512) ((float*)acc)[k] = 0.f;
  __syncthreads();
  // ---------------- phase A: per-instance stats ----------------
  int w = wid;
#define ACC(L, X, Y, SG)                                                   \
    if (L > 0) {                                                           \
      atomicAdd(&acc[w][L], X);        atomicAdd(&acc[w][33 + L], Y);      \
      atomicAdd(&acc[w][66 + L], SG);  atomicAdd(&acc[w][99 + L], (SG)*(SG)); \
      atomicAdd(&acc[w][132 + L], 1.0f);                                   \
    }
  ACC(lbl0.x, px0.x, py0.x, sg0.x)
  ACC(lbl0.y, px0.y, py0.y, sg0.y)
  ACC(lbl0.z, px0.z, py0.z, sg0.z)
  ACC(lbl0.w, px0.w, py0.w, sg0.w)
  ACC(lbl1.x, px1.x, py1.x, sg1.x)
  ACC(lbl1.y, px1.y, py1.y, sg1.y)
  ACC(lbl1.z, px1.z, py1.z, sg1.z)
  ACC(lbl1.w, px1.w, py1.w, sg1.w)
#undef ACC
  __syncthreads();
  if (t < 165) {
    float v = acc[0][t] + acc[1][t] + acc[2][t] + acc[3][t]
            + acc[4][t] + acc[5][t] + acc[6][t] + acc[7][t];
    ws[W_PART + s * PS + lb * PJ + t] = v;   // plain store, unique slot
  }
  __syncthreads();   // drains all global stores (t-hist zero + partial)
  if (t == 0) {
    __threadfence();   // release before arrival
    isred = (atomicAdd(wsu + W_CNTA + s, 1u) == 63u);
  }
  __syncthreads();
  // zero LDS hist while the reducer works / before spinning
  for (int k = t; k < NB * 8; k += 512) hist[k] = 0u;
  if (isred) {
    // ---- last-arriving block: reduce 64 partials -> cons + vart ----
    __threadfence();   // acquire partials
    if (t < 330) {
      int r = (t >= 165) ? 1 : 0;
      int c = t - r * 165;
      const float* pp = ws + W_PART + s * PS + (r * 32) * PJ + c;
      float sum = 0.f;
      #pragma unroll 8
      for (int jj = 0; jj < 32; ++jj) sum += pp[jj * PJ];
      sums2[r][c] = sum;
    }
    __syncthreads();
    if (t < 165) sums[t] = sums2[0][t] + sums2[1][t];
    __syncthreads();
    if (t >= 1 && t < NC) {
      float c = sums[132 + t];
      float4 C;
      if (c > 0.f) {
        float inv = 1.0f / c;
        float c0 = sums[t] * inv, c1 = sums[33 + t] * inv, sgm = sums[66 + t] * inv;
        float Q = 0.5f / (sgm * sgm) * BSCALE;
        C.x = Q; C.y = -2.0f * Q * c0; C.z = -2.0f * Q * c1;
        C.w = Q * (c0 * c0 + c1 * c1);
      } else {
        C.x = 0.f; C.y = 0.f; C.z = 0.f; C.w = (float)NB;  // last bin, e~0
      }
      ((float4*)(ws + W_CONS))[s * NC + t] = C;
    }
    if (wid == 0) {   // pooled variance: vart = S_total * (sum 1/c) / NI
      float S = 0.f, rcp = 0.f;
      if (lane >= 1 && lane < NC) {
        float c = sums[132 + lane];
        if (c > 0.f) {
          float sg = sums[66 + lane] / c;
          S = sums[99 + lane] - c * sg * sg;
          rcp = 1.0f / c;
        }
      }
      for (int o = 32; o; o >>= 1) {
        S   += __shfl_down(S, o);
        rcp += __shfl_down(rcp, o);
      }
      if (lane == 0) ws[W_VART + s] = S * rcp / (float)NI;
    }
    __syncthreads();
    if (t == 0) {
      __threadfence();   // release cons + vart
      atomicExch(wsu + W_CRDY + s, 1u);
    }
  }
  // ---- spin until cons ready (all 256 blocks co-resident: safe) ----
  if (t == 0) {
    while (atomicAdd(wsu + W_CRDY + s, 0u) == 0u) __builtin_amdgcn_s_sleep(2);
  }
  __syncthreads();
  __threadfence();   // acquire cons
  if (t < NC) consS[t] = ((const float4*)(ws + W_CONS))[s * NC + t];
  float4 ss0, ss1;
  ss0.x = fmaf(px0.x, px0.x, py0.x * py0.x);
  ss0.y = fmaf(px0.y, px0.y, py0.y * py0.y);
  ss0.z = fmaf(px0.z, px0.z, py0.z * py0.z);
  ss0.w = fmaf(px0.w, px0.w, py0.w * py0.w);
  ss1.x = fmaf(px1.x, px1.x, py1.x * py1.x);
  ss1.y = fmaf(px1.y, px1.y, py1.y * py1.y);
  ss1.z = fmaf(px1.z, px1.z, py1.z * py1.z);
  ss1.w = fmaf(px1.w, px1.w, py1.w * py1.w);
  __syncthreads();
  // ---------------- phase B: histogram ----------------
  unsigned* hr = hist + (t & 7);
  // positive-item correction: the n-loop adds 1 (neg) for every item,
  // including the pixel's own instance; add 0xFFFF at the same bin so the
  // total becomes 0x10000 (one pos, zero neg) for the pos item.
#define POSFIX(P0, P1, SV, L)                                            \
    if (L > 0) {                                                         \
      float4 C = consS[L];                                               \
      float bf = fmaf(C.x, SV, fmaf(C.y, P0, fmaf(C.z, P1, C.w)));       \
      int ib = min((int)bf, NB - 1);                                     \
      atomicAdd(&hr[ib << 3], 0xFFFFu);                                  \
    }
  POSFIX(px0.x, py0.x, ss0.x, lbl0.x)
  POSFIX(px0.y, py0.y, ss0.y, lbl0.y)
  POSFIX(px0.z, py0.z, ss0.z, lbl0.z)
  POSFIX(px0.w, py0.w, ss0.w, lbl0.w)
  POSFIX(px1.x, py1.x, ss1.x, lbl1.x)
  POSFIX(px1.y, py1.y, ss1.y, lbl1.y)
  POSFIX(px1.z, py1.z, ss1.z, lbl1.z)
  POSFIX(px1.w, py1.w, ss1.w, lbl1.w)
#undef POSFIX
  #pragma unroll 4
  for (int n = 1; n <= NI; ++n) {
    float4 C = consS[n];
    // branchless: clamp to last bin; far items land at e~2e-7, processed
    // last in the descending scan where p==P already -> contribution ~0.
#define ITEM(P0, P1, SV)                                               \
    {                                                                  \
      float bf = fmaf(C.x, SV, fmaf(C.y, P0, fmaf(C.z, P1, C.w)));     \
      int ib = min((int)bf, NB - 1);                                   \
      atomicAdd(&hr[ib << 3], 1u);                                     \
    }
    ITEM(px0.x, py0.x, ss0.x)
    ITEM(px0.y, py0.y, ss0.y)
    ITEM(px0.z, py0.z, ss0.z)
    ITEM(px0.w, py0.w, ss0.w)
    ITEM(px1.x, py1.x, ss1.x)
    ITEM(px1.y, py1.y, ss1.y)
    ITEM(px1.z, py1.z, ss1.z)
    ITEM(px1.w, py1.w, ss1.w)
#undef ITEM
  }
  __syncthreads();
  // flush to the sample's global t-hist (device-scope u64 atomics:
  // pre-merges across blocks so the tail reads only 8 KB)
  ull* th = ((ull*)ws) + (size_t)s * NB;
  for (int k = t; k < NB; k += 512) {
    uint4 a = *(uint4*)&hist[k * 8];
    uint4 b = *(uint4*)&hist[k * 8 + 4];
    unsigned v = a.x + a.y + a.z + a.w + b.x + b.y + b.z + b.w;
    if (v) {
      ull add = ((ull)(v >> 16) << 32) | (v & 0xFFFFu);
      atomicAdd(&th[k], add);
    }
  }
  __syncthreads();
  if (t == 0) {
    __threadfence();   // release our (atomic) flush before arrival
    flag = (atomicAdd(wsu + W_CNTB + s, 1u) == 63u);
  }
  __syncthreads();
  if (!flag) return;

  // ================= scan phase (one block per sample) =================
  unsigned* ep = hist;
  unsigned* en = hist + EG;
  for (int k = t; k < 2 * EG; k += 512) hist[k] = 0u;
  float vart = ws[W_VART + s];
  __syncthreads();
  // read global t-hist (atomic reads for cross-XCD coherence), scatter to e-grid
  for (int b = t; b < NB; b += 512) {
    ull v = atomicAdd(&th[b], 0ull);
    unsigned pos = (unsigned)(v >> 32), neg = (unsigned)(v & 0xFFFFFFFFu);
    if (pos | neg) {
      float tc = ((float)b + 0.5f) * (1.0f / BSCALE);
      float ex = __expf(-tc);
      if (pos) {
        float e = 2.0f - 2.0f * ex;
        int k = (int)(e * ESCALE); if (k > EG - 1) k = EG - 1;
        atomicAdd(&ep[k], pos);
      }
      if (neg) {
        float e = 2.0f * ex;
        int k = (int)(e * ESCALE); if (k > EG - 1) k = EG - 1;
        atomicAdd(&en[k], neg);
      }
    }
  }
  __syncthreads();
  const int CH = EG / 512;  // 8
  int j0 = t * CH;
  unsigned np = 0, nn = 0;
  for (int k = 0; k < CH; ++k) {
    int b = EG - 1 - (j0 + k);
    np += ep[b]; nn += en[b];
  }
  ull v = ((ull)np << 32) | (ull)nn;
  ull inc = v;
  for (int o = 1; o < 64; o <<= 1) {
    ull u = __shfl_up(inc, o);
    if (lane >= o) inc += u;
  }
  if (lane == 63) wsum[wid] = inc;
  __syncthreads();
  ull offset = 0, total = 0;
  for (int i = 0; i < 8; ++i) {
    ull xr = wsum[i];
    if (i < wid) offset += xr;
    total += xr;
  }
  ull excl = offset + inc - v;
  float P = (float)(unsigned)(total >> 32);
  unsigned p = (unsigned)(excl >> 32), f = (unsigned)(excl & 0xFFFFFFFFu);
  float jprev = 1.0f - (P - (float)p) / (P + (float)f);
  float contrib = 0.f;
  for (int k = 0; k < CH; ++k) {
    int b = EG - 1 - (j0 + k);
    unsigned ap_ = ep[b], an_ = en[b];
    if (ap_ | an_) {
      p += ap_; f += an_;
      float j = 1.0f - (P - (float)p) / (P + (float)f);
      float e = ((float)b + 0.5f) * (2.0f / EG);
      contrib += e * (j - jprev);
      jprev = j;
    }
  }
  for (int o = 32; o; o >>= 1) contrib += __shfl_down(contrib, o);
  if (lane == 0) red[wid] = contrib;
  __syncthreads();
  if (t == 0) {
    float tot = 0.f;
    for (int i = 0; i < 8; ++i) tot += red[i];
    float loss = tot + vart;
    float* fin = ws + W_FINL;
    atomicExch(&fin[s], loss);
    __threadfence();
    unsigned old = atomicAdd(wsu + W_CNTF, 1u);
    if (old == BNUM - 1) {
      float a = 0.f;
      for (int i = 0; i < BNUM; ++i) a += atomicAdd(&fin[i], 0.0f);
      out[0] = a * (1.0f / BNUM);
    }
  }
}

extern "C" void kernel_launch(void* const* d_in, const int* in_sizes, int n_in,
                              void* d_out, int out_size, void* d_ws, size_t ws_size,
                              hipStream_t stream) {
  const float* emb = (const float*)d_in[0];   // [4,2,512,512]
  const float* sig = (const float*)d_in[1];   // [4,1,512,512]
  const int*   gt  = (const int*)d_in[2];     // [4,1,512,512]
  float* out = (float*)d_out;
  float* ws  = (float*)d_ws;

  init_kernel<<<1, 64, 0, stream>>>(ws);
  dim3 g(64, BNUM);   // 256 blocks = 1 per CU
  fused_kernel<<<g, 512, 0, stream>>>(emb, sig, gt, ws, out);
}

// Round 9
// 143.114 us; speedup vs baseline: 1.0284x; 1.0284x over previous
//
#include <hip/hip_runtime.h>

#define HW    262144      // 512*512
#define BNUM  4
#define NC    33          // labels 0..32
#define NI    32          // instance channels

#define NB     1024       // t-space bins
#define BSCALE 64.0f      // NB / TMAX (TMAX = 16)
#define EG     4096       // e-grid bins in scan
#define ESCALE 2048.0f    // EG / 2.0

typedef unsigned long long ull;

// ws layout in 32-bit words. Sync words padded to one 128B line each:
//   [0 .. 8192)    t-hist: u64[NB] per sample (zeroed in-kernel pre-sync)
//   [8192..8320)   cntA[s] at 8192+s*32   phase-A arrival counters
//   [8320..8448)   crdy[s] at 8320+s*32   cons-ready flags
//   [8448..8576)   cntB[s] at 8448+s*32   phase-B arrival counters
//   [8576]         cntF                    finalize counter
//   [8608..8612)   fin[s]  per-sample losses
//   [8616..8620)   vart[s] pooled variance term
//   [8624..9152)   cons float4[s][NC]
//   [9152.. )      partials float[s][64][168]
#define W_CNTA 8192
#define W_CRDY 8320
#define W_CNTB 8448
#define W_CNTF 8576
#define W_FINL 8608
#define W_VART 8616
#define W_CONS 8624
#define W_PART 9152
#define PJ 168            // padded words per partial slot (165 used)
#define PS (64 * PJ)      // words per sample

// ---------------- K0: zero the sync counters (one wave).
__global__ void __launch_bounds__(64) init_kernel(float* __restrict__ ws) {
  unsigned* wsu = (unsigned*)ws;
  int t = threadIdx.x;
  for (int k = t; k < 416; k += 64) wsu[W_CNTA + k] = 0u;  // 8192..8608
}

// ---------------- Fused: stats -> (last block: cons+vart) -> load-spin ->
// hist -> u64 flush -> (last block: scan). Grid = 256 blocks = #CUs,
// 8 waves, ~41 KB LDS: all blocks co-resident, spin cannot deadlock.
__global__ void __launch_bounds__(512) fused_kernel(
    const float* __restrict__ emb, const float* __restrict__ sig,
    const int* __restrict__ gt, float* __restrict__ ws,
    float* __restrict__ out) {
  int s  = blockIdx.y;
  int lb = blockIdx.x;           // 0..63
  int t = threadIdx.x;
  int lane = t & 63, wid = t >> 6;
  __shared__ float acc[8][165];       // phase-A per-wave accumulators
  __shared__ unsigned hist[NB * 8];   // 32 KB; aliased as e-grid in tail
  __shared__ float sums2[2][165];
  __shared__ float sums[165];
  __shared__ float4 consS[NC];
  __shared__ ull wsum[8];
  __shared__ float red[8];
  __shared__ int isred, flag;
  unsigned* wsu = (unsigned*)ws;

  const float* e0p = emb + (size_t)s * 2 * HW;
  const float* e1p = e0p + HW;
  const float* sp  = sig + (size_t)s * HW;
  const int*   gp  = gt  + (size_t)s * HW;
  // prefetch 8 px/thread: loads issued before LDS init
  int base = lb * 4096 + t * 4;
  int4   lbl0 = *(const int4*)(gp + base);
  int4   lbl1 = *(const int4*)(gp + base + 2048);
  float4 px0  = *(const float4*)(e0p + base);
  float4 px1  = *(const float4*)(e0p + base + 2048);
  float4 py0  = *(const float4*)(e1p + base);
  float4 py1  = *(const float4*)(e1p + base + 2048);
  float4 sg0  = *(const float4*)(sp + base);
  float4 sg1  = *(const float4*)(sp + base + 2048);
  // zero this block's slice of the global t-hist (32 words each = 16 bins;
  // 64 blocks cover the sample's 1024 bins; ordered before any phase-B
  // atomic via the release->arrival->crdy sync chain)
  if (t < 32) wsu[(s * 64 + lb) * 32 + t] = 0u;
  for (int k = t; k < 8 * 165; k += 512) ((float*)acc)[k] = 0.f;
  __syncthreads();
  // ---------------- phase A: per-instance stats ----------------
  int w = wid;
#define ACC(L, X, Y, SG)                                                   \
    if (L > 0) {                                                           \
      atomicAdd(&acc[w][L], X);        atomicAdd(&acc[w][33 + L], Y);      \
      atomicAdd(&acc[w][66 + L], SG);  atomicAdd(&acc[w][99 + L], (SG)*(SG)); \
      atomicAdd(&acc[w][132 + L], 1.0f);                                   \
    }
  ACC(lbl0.x, px0.x, py0.x, sg0.x)
  ACC(lbl0.y, px0.y, py0.y, sg0.y)
  ACC(lbl0.z, px0.z, py0.z, sg0.z)
  ACC(lbl0.w, px0.w, py0.w, sg0.w)
  ACC(lbl1.x, px1.x, py1.x, sg1.x)
  ACC(lbl1.y, px1.y, py1.y, sg1.y)
  ACC(lbl1.z, px1.z, py1.z, sg1.z)
  ACC(lbl1.w, px1.w, py1.w, sg1.w)
#undef ACC
  __syncthreads();
  if (t < 165) {
    float v = acc[0][t] + acc[1][t] + acc[2][t] + acc[3][t]
            + acc[4][t] + acc[5][t] + acc[6][t] + acc[7][t];
    ws[W_PART + s * PS + lb * PJ + t] = v;   // plain store, unique slot
  }
  __syncthreads();   // all stores issued (t-hist zero + partial)
  if (t == 0) {
    __threadfence();   // release before arrival
    isred = (atomicAdd(wsu + W_CNTA + s * 32, 1u) == 63u);
  }
  __syncthreads();
  // zero LDS hist while the reducer works / before spinning
  for (int k = t; k < NB * 8; k += 512) hist[k] = 0u;
  if (isred) {
    // ---- last-arriving block: reduce 64 partials -> cons + vart ----
    __threadfence();   // acquire partials
    if (t < 330) {
      int r = (t >= 165) ? 1 : 0;
      int c = t - r * 165;
      const float* pp = ws + W_PART + s * PS + (r * 32) * PJ + c;
      float sum = 0.f;
      #pragma unroll 8
      for (int jj = 0; jj < 32; ++jj) sum += pp[jj * PJ];
      sums2[r][c] = sum;
    }
    __syncthreads();
    if (t < 165) sums[t] = sums2[0][t] + sums2[1][t];
    __syncthreads();
    if (t >= 1 && t < NC) {
      float c = sums[132 + t];
      float4 C;
      if (c > 0.f) {
        float inv = 1.0f / c;
        float c0 = sums[t] * inv, c1 = sums[33 + t] * inv, sgm = sums[66 + t] * inv;
        float Q = 0.5f / (sgm * sgm) * BSCALE;
        C.x = Q; C.y = -2.0f * Q * c0; C.z = -2.0f * Q * c1;
        C.w = Q * (c0 * c0 + c1 * c1);
      } else {
        C.x = 0.f; C.y = 0.f; C.z = 0.f; C.w = (float)NB;  // last bin, e~0
      }
      ((float4*)(ws + W_CONS))[s * NC + t] = C;
    }
    if (wid == 0) {   // pooled variance: vart = S_total * (sum 1/c) / NI
      float S = 0.f, rcp = 0.f;
      if (lane >= 1 && lane < NC) {
        float c = sums[132 + lane];
        if (c > 0.f) {
          float sg = sums[66 + lane] / c;
          S = sums[99 + lane] - c * sg * sg;
          rcp = 1.0f / c;
        }
      }
      for (int o = 32; o; o >>= 1) {
        S   += __shfl_down(S, o);
        rcp += __shfl_down(rcp, o);
      }
      if (lane == 0) ws[W_VART + s] = S * rcp / (float)NI;
    }
    __syncthreads();
    if (t == 0) {
      __threadfence();   // release cons + vart
      atomicExch(wsu + W_CRDY + s * 32, 1u);
    }
  }
  // ---- spin until cons ready: relaxed agent-scope LOAD (no RMW, no
  // ownership transfer -> LLC serves all 256 spinners concurrently) ----
  if (t == 0) {
    while (__hip_atomic_load(wsu + W_CRDY + s * 32,
             __ATOMIC_RELAXED, __HIP_MEMORY_SCOPE_AGENT) == 0u)
      __builtin_amdgcn_s_sleep(8);
  }
  __syncthreads();
  __threadfence();   // acquire cons
  if (t < NC) consS[t] = ((const float4*)(ws + W_CONS))[s * NC + t];
  float4 ss0, ss1;
  ss0.x = fmaf(px0.x, px0.x, py0.x * py0.x);
  ss0.y = fmaf(px0.y, px0.y, py0.y * py0.y);
  ss0.z = fmaf(px0.z, px0.z, py0.z * py0.z);
  ss0.w = fmaf(px0.w, px0.w, py0.w * py0.w);
  ss1.x = fmaf(px1.x, px1.x, py1.x * py1.x);
  ss1.y = fmaf(px1.y, px1.y, py1.y * py1.y);
  ss1.z = fmaf(px1.z, px1.z, py1.z * py1.z);
  ss1.w = fmaf(px1.w, px1.w, py1.w * py1.w);
  __syncthreads();
  // ---------------- phase B: histogram ----------------
  unsigned* hr = hist + (t & 7);
  // positive-item correction: the n-loop adds 1 (neg) for every item,
  // including the pixel's own instance; add 0xFFFF at the same bin so the
  // total becomes 0x10000 (one pos, zero neg) for the pos item.
#define POSFIX(P0, P1, SV, L)                                            \
    if (L > 0) {                                                         \
      float4 C = consS[L];                                               \
      float bf = fmaf(C.x, SV, fmaf(C.y, P0, fmaf(C.z, P1, C.w)));       \
      int ib = min((int)bf, NB - 1);                                     \
      atomicAdd(&hr[ib << 3], 0xFFFFu);                                  \
    }
  POSFIX(px0.x, py0.x, ss0.x, lbl0.x)
  POSFIX(px0.y, py0.y, ss0.y, lbl0.y)
  POSFIX(px0.z, py0.z, ss0.z, lbl0.z)
  POSFIX(px0.w, py0.w, ss0.w, lbl0.w)
  POSFIX(px1.x, py1.x, ss1.x, lbl1.x)
  POSFIX(px1.y, py1.y, ss1.y, lbl1.y)
  POSFIX(px1.z, py1.z, ss1.z, lbl1.z)
  POSFIX(px1.w, py1.w, ss1.w, lbl1.w)
#undef POSFIX
  #pragma unroll 4
  for (int n = 1; n <= NI; ++n) {
    float4 C = consS[n];
    // branchless: clamp to last bin; far items land at e~2e-7, processed
    // last in the descending scan where p==P already -> contribution ~0.
#define ITEM(P0, P1, SV)                                               \
    {                                                                  \
      float bf = fmaf(C.x, SV, fmaf(C.y, P0, fmaf(C.z, P1, C.w)));     \
      int ib = min((int)bf, NB - 1);                                   \
      atomicAdd(&hr[ib << 3], 1u);                                     \
    }
    ITEM(px0.x, py0.x, ss0.x)
    ITEM(px0.y, py0.y, ss0.y)
    ITEM(px0.z, py0.z, ss0.z)
    ITEM(px0.w, py0.w, ss0.w)
    ITEM(px1.x, py1.x, ss1.x)
    ITEM(px1.y, py1.y, ss1.y)
    ITEM(px1.z, py1.z, ss1.z)
    ITEM(px1.w, py1.w, ss1.w)
#undef ITEM
  }
  __syncthreads();
  // flush to the sample's global t-hist (device-scope u64 atomics:
  // pre-merges across blocks so the tail reads only 8 KB)
  ull* th = ((ull*)ws) + (size_t)s * NB;
  for (int k = t; k < NB; k += 512) {
    uint4 a = *(uint4*)&hist[k * 8];
    uint4 b = *(uint4*)&hist[k * 8 + 4];
    unsigned v = a.x + a.y + a.z + a.w + b.x + b.y + b.z + b.w;
    if (v) {
      ull add = ((ull)(v >> 16) << 32) | (v & 0xFFFFu);
      atomicAdd(&th[k], add);
    }
  }
  __syncthreads();
  if (t == 0) {
    __threadfence();   // release our (atomic) flush before arrival
    flag = (atomicAdd(wsu + W_CNTB + s * 32, 1u) == 63u);
  }
  __syncthreads();
  if (!flag) return;

  // ================= scan phase (one block per sample) =================
  unsigned* ep = hist;
  unsigned* en = hist + EG;
  for (int k = t; k < 2 * EG; k += 512) hist[k] = 0u;
  float vart = ws[W_VART + s];
  __syncthreads();
  // read global t-hist (atomic reads for cross-XCD coherence), scatter to e-grid
  for (int b = t; b < NB; b += 512) {
    ull v = atomicAdd(&th[b], 0ull);
    unsigned pos = (unsigned)(v >> 32), neg = (unsigned)(v & 0xFFFFFFFFu);
    if (pos | neg) {
      float tc = ((float)b + 0.5f) * (1.0f / BSCALE);
      float ex = __expf(-tc);
      if (pos) {
        float e = 2.0f - 2.0f * ex;
        int k = (int)(e * ESCALE); if (k > EG - 1) k = EG - 1;
        atomicAdd(&ep[k], pos);
      }
      if (neg) {
        float e = 2.0f * ex;
        int k = (int)(e * ESCALE); if (k > EG - 1) k = EG - 1;
        atomicAdd(&en[k], neg);
      }
    }
  }
  __syncthreads();
  const int CH = EG / 512;  // 8
  int j0 = t * CH;
  unsigned np = 0, nn = 0;
  for (int k = 0; k < CH; ++k) {
    int b = EG - 1 - (j0 + k);
    np += ep[b]; nn += en[b];
  }
  ull v = ((ull)np << 32) | (ull)nn;
  ull inc = v;
  for (int o = 1; o < 64; o <<= 1) {
    ull u = __shfl_up(inc, o);
    if (lane >= o) inc += u;
  }
  if (lane == 63) wsum[wid] = inc;
  __syncthreads();
  ull offset = 0, total = 0;
  for (int i = 0; i < 8; ++i) {
    ull xr = wsum[i];
    if (i < wid) offset += xr;
    total += xr;
  }
  ull excl = offset + inc - v;
  float P = (float)(unsigned)(total >> 32);
  unsigned p = (unsigned)(excl >> 32), f = (unsigned)(excl & 0xFFFFFFFFu);
  float jprev = 1.0f - (P - (float)p) / (P + (float)f);
  float contrib = 0.f;
  for (int k = 0; k < CH; ++k) {
    int b = EG - 1 - (j0 + k);
    unsigned ap_ = ep[b], an_ = en[b];
    if (ap_ | an_) {
      p += ap_; f += an_;
      float j = 1.0f - (P - (float)p) / (P + (float)f);
      float e = ((float)b + 0.5f) * (2.0f / EG);
      contrib += e * (j - jprev);
      jprev = j;
    }
  }
  for (int o = 32; o; o >>= 1) contrib += __shfl_down(contrib, o);
  if (lane == 0) red[wid] = contrib;
  __syncthreads();
  if (t == 0) {
    float tot = 0.f;
    for (int i = 0; i < 8; ++i) tot += red[i];
    float loss = tot + vart;
    float* fin = ws + W_FINL;
    atomicExch(&fin[s], loss);
    __threadfence();
    unsigned old = atomicAdd(wsu + W_CNTF, 1u);
    if (old == BNUM - 1) {
      float a = 0.f;
      for (int i = 0; i < BNUM; ++i) a += atomicAdd(&fin[i], 0.0f);
      out[0] = a * (1.0f / BNUM);
    }
  }
}

extern "C" void kernel_launch(void* const* d_in, const int* in_sizes, int n_in,
                              void* d_out, int out_size, void* d_ws, size_t ws_size,
                              hipStream_t stream) {
  const float* emb = (const float*)d_in[0];   // [4,2,512,512]
  const float* sig = (const float*)d_in[1];   // [4,1,512,512]
  const int*   gt  = (const int*)d_in[2];     // [4,1,512,512]
  float* out = (float*)d_out;
  float* ws  = (float*)d_ws;

  init_kernel<<<1, 64, 0, stream>>>(ws);
  dim3 g(64, BNUM);   // 256 blocks = 1 per CU
  fused_kernel<<<g, 512, 0, stream>>>(emb, sig, gt, ws, out);
}

// Round 10
// 140.771 us; speedup vs baseline: 1.0455x; 1.0166x over previous
//
#include <hip/hip_runtime.h>

#define HW    262144      // 512*512
#define BNUM  4
#define NC    33          // labels 0..32
#define NI    32          // instance channels

#define NB     1024       // t-space bins
#define BSCALE 64.0f      // NB / TMAX (TMAX = 16)
#define EG     4096       // e-grid bins in scan
#define ESCALE 2048.0f    // EG / 2.0

typedef unsigned long long ull;

// ws layout in 32-bit words. Sync words padded to one 128B line each:
//   [0 .. 8192)    t-hist: u64[NB] per sample (zeroed in-kernel pre-sync)
//   [8192..8320)   cntA[s] at 8192+s*32   phase-A arrival counters
//   [8320..8448)   crdy[s] at 8320+s*32   cons-ready flags
//   [8448..8576)   cntB[s] at 8448+s*32   phase-B arrival counters
//   [8576]         cntF                    finalize counter
//   [8608..8612)   fin[s]  per-sample losses
//   [8616..8620)   vart[s] pooled variance term
//   [8624..9152)   cons float4[s][NC]
//   [9152.. )      partials float[s][64][168]
#define W_CNTA 8192
#define W_CRDY 8320
#define W_CNTB 8448
#define W_CNTF 8576
#define W_FINL 8608
#define W_VART 8616
#define W_CONS 8624
#define W_PART 9152
#define PJ 168            // padded words per partial slot (165 used)
#define PS (64 * PJ)      // words per sample

// ---------------- K0: zero the sync counters (one wave).
__global__ void __launch_bounds__(64) init_kernel(float* __restrict__ ws) {
  unsigned* wsu = (unsigned*)ws;
  int t = threadIdx.x;
  for (int k = t; k < 416; k += 64) wsu[W_CNTA + k] = 0u;  // 8192..8608
}

// ---------------- Fused: stats -> (last block: cons+vart) -> load-spin ->
// hist -> u64 flush -> (last block: scan). Grid = 256 blocks = #CUs,
// 8 waves, ~41 KB LDS: all blocks co-resident, spin cannot deadlock.
// KEY: every global store before a __threadfence is a write-through
// agent-scope atomic store -> L2 never dirty -> fences are cheap
// (round-7 K2's proven-fast configuration; dirty stores were the 86us bug).
__global__ void __launch_bounds__(512) fused_kernel(
    const float* __restrict__ emb, const float* __restrict__ sig,
    const int* __restrict__ gt, float* __restrict__ ws,
    float* __restrict__ out) {
  int s  = blockIdx.y;
  int lb = blockIdx.x;           // 0..63
  int t = threadIdx.x;
  int lane = t & 63, wid = t >> 6;
  __shared__ float acc[8][165];       // phase-A per-wave accumulators
  __shared__ unsigned hist[NB * 8];   // 32 KB; aliased as e-grid in tail
  __shared__ float sums2[2][165];
  __shared__ float sums[165];
  __shared__ float4 consS[NC];
  __shared__ ull wsum[8];
  __shared__ float red[8];
  __shared__ int isred, flag;
  unsigned* wsu = (unsigned*)ws;

  const float* e0p = emb + (size_t)s * 2 * HW;
  const float* e1p = e0p + HW;
  const float* sp  = sig + (size_t)s * HW;
  const int*   gp  = gt  + (size_t)s * HW;
  // prefetch 8 px/thread: loads issued before LDS init
  int base = lb * 4096 + t * 4;
  int4   lbl0 = *(const int4*)(gp + base);
  int4   lbl1 = *(const int4*)(gp + base + 2048);
  float4 px0  = *(const float4*)(e0p + base);
  float4 px1  = *(const float4*)(e0p + base + 2048);
  float4 py0  = *(const float4*)(e1p + base);
  float4 py1  = *(const float4*)(e1p + base + 2048);
  float4 sg0  = *(const float4*)(sp + base);
  float4 sg1  = *(const float4*)(sp + base + 2048);
  // zero this block's slice of the global t-hist (write-through, no dirty L2)
  if (t < 32)
    __hip_atomic_store(wsu + (s * 64 + lb) * 32 + t, 0u,
                       __ATOMIC_RELAXED, __HIP_MEMORY_SCOPE_AGENT);
  for (int k = t; k < 8 * 165; k += 512) ((float*)acc)[k] = 0.f;
  __syncthreads();
  // ---------------- phase A: per-instance stats ----------------
  int w = wid;
#define ACC(L, X, Y, SG)                                                   \
    if (L > 0) {                                                           \
      atomicAdd(&acc[w][L], X);        atomicAdd(&acc[w][33 + L], Y);      \
      atomicAdd(&acc[w][66 + L], SG);  atomicAdd(&acc[w][99 + L], (SG)*(SG)); \
      atomicAdd(&acc[w][132 + L], 1.0f);                                   \
    }
  ACC(lbl0.x, px0.x, py0.x, sg0.x)
  ACC(lbl0.y, px0.y, py0.y, sg0.y)
  ACC(lbl0.z, px0.z, py0.z, sg0.z)
  ACC(lbl0.w, px0.w, py0.w, sg0.w)
  ACC(lbl1.x, px1.x, py1.x, sg1.x)
  ACC(lbl1.y, px1.y, py1.y, sg1.y)
  ACC(lbl1.z, px1.z, py1.z, sg1.z)
  ACC(lbl1.w, px1.w, py1.w, sg1.w)
#undef ACC
  __syncthreads();
  if (t < 165) {
    float v = acc[0][t] + acc[1][t] + acc[2][t] + acc[3][t]
            + acc[4][t] + acc[5][t] + acc[6][t] + acc[7][t];
    // write-through store to unique slot: visible at LLC, L2 stays clean
    __hip_atomic_store(ws + W_PART + s * PS + lb * PJ + t, v,
                       __ATOMIC_RELAXED, __HIP_MEMORY_SCOPE_AGENT);
  }
  __syncthreads();   // all stores issued (t-hist zero + partial)
  if (t == 0) {
    __threadfence();   // release before arrival (clean L2 -> cheap)
    isred = (atomicAdd(wsu + W_CNTA + s * 32, 1u) == 63u);
  }
  __syncthreads();
  // zero LDS hist while the reducer works / before spinning
  for (int k = t; k < NB * 8; k += 512) hist[k] = 0u;
  if (isred) {
    // ---- last-arriving block: reduce 64 partials -> cons + vart ----
    __threadfence();   // acquire partials (4 blocks only)
    if (t < 330) {
      int r = (t >= 165) ? 1 : 0;
      int c = t - r * 165;
      const float* pp = ws + W_PART + s * PS + (r * 32) * PJ + c;
      float sum = 0.f;
      #pragma unroll 8
      for (int jj = 0; jj < 32; ++jj) sum += pp[jj * PJ];
      sums2[r][c] = sum;
    }
    __syncthreads();
    if (t < 165) sums[t] = sums2[0][t] + sums2[1][t];
    __syncthreads();
    if (t >= 1 && t < NC) {
      float c = sums[132 + t];
      float4 C;
      if (c > 0.f) {
        float inv = 1.0f / c;
        float c0 = sums[t] * inv, c1 = sums[33 + t] * inv, sgm = sums[66 + t] * inv;
        float Q = 0.5f / (sgm * sgm) * BSCALE;
        C.x = Q; C.y = -2.0f * Q * c0; C.z = -2.0f * Q * c1;
        C.w = Q * (c0 * c0 + c1 * c1);
      } else {
        C.x = 0.f; C.y = 0.f; C.z = 0.f; C.w = (float)NB;  // last bin, e~0
      }
      // write-through: 4 words per thread, keeps L2 clean for the release
      float* cd = ws + W_CONS + (s * NC + t) * 4;
      __hip_atomic_store(cd + 0, C.x, __ATOMIC_RELAXED, __HIP_MEMORY_SCOPE_AGENT);
      __hip_atomic_store(cd + 1, C.y, __ATOMIC_RELAXED, __HIP_MEMORY_SCOPE_AGENT);
      __hip_atomic_store(cd + 2, C.z, __ATOMIC_RELAXED, __HIP_MEMORY_SCOPE_AGENT);
      __hip_atomic_store(cd + 3, C.w, __ATOMIC_RELAXED, __HIP_MEMORY_SCOPE_AGENT);
    }
    if (wid == 0) {   // pooled variance: vart = S_total * (sum 1/c) / NI
      float S = 0.f, rcp = 0.f;
      if (lane >= 1 && lane < NC) {
        float c = sums[132 + lane];
        if (c > 0.f) {
          float sg = sums[66 + lane] / c;
          S = sums[99 + lane] - c * sg * sg;
          rcp = 1.0f / c;
        }
      }
      for (int o = 32; o; o >>= 1) {
        S   += __shfl_down(S, o);
        rcp += __shfl_down(rcp, o);
      }
      if (lane == 0)
        __hip_atomic_store(ws + W_VART + s, S * rcp / (float)NI,
                           __ATOMIC_RELAXED, __HIP_MEMORY_SCOPE_AGENT);
    }
    __syncthreads();
    if (t == 0) {
      __threadfence();   // release cons + vart (clean L2 -> cheap)
      atomicExch(wsu + W_CRDY + s * 32, 1u);
    }
  }
  // ---- spin until cons ready: relaxed agent-scope LOAD (no RMW) ----
  if (t == 0) {
    while (__hip_atomic_load(wsu + W_CRDY + s * 32,
             __ATOMIC_RELAXED, __HIP_MEMORY_SCOPE_AGENT) == 0u)
      __builtin_amdgcn_s_sleep(2);
  }
  __syncthreads();
  __threadfence();   // acquire cons (L2 clean everywhere -> cheap)
  if (t < NC) consS[t] = ((const float4*)(ws + W_CONS))[s * NC + t];
  float4 ss0, ss1;
  ss0.x = fmaf(px0.x, px0.x, py0.x * py0.x);
  ss0.y = fmaf(px0.y, px0.y, py0.y * py0.y);
  ss0.z = fmaf(px0.z, px0.z, py0.z * py0.z);
  ss0.w = fmaf(px0.w, px0.w, py0.w * py0.w);
  ss1.x = fmaf(px1.x, px1.x, py1.x * py1.x);
  ss1.y = fmaf(px1.y, px1.y, py1.y * py1.y);
  ss1.z = fmaf(px1.z, px1.z, py1.z * py1.z);
  ss1.w = fmaf(px1.w, px1.w, py1.w * py1.w);
  __syncthreads();
  // ---------------- phase B: histogram ----------------
  unsigned* hr = hist + (t & 7);
  // positive-item correction: the n-loop adds 1 (neg) for every item,
  // including the pixel's own instance; add 0xFFFF at the same bin so the
  // total becomes 0x10000 (one pos, zero neg) for the pos item.
#define POSFIX(P0, P1, SV, L)                                            \
    if (L > 0) {                                                         \
      float4 C = consS[L];                                               \
      float bf = fmaf(C.x, SV, fmaf(C.y, P0, fmaf(C.z, P1, C.w)));       \
      int ib = min((int)bf, NB - 1);                                     \
      atomicAdd(&hr[ib << 3], 0xFFFFu);                                  \
    }
  POSFIX(px0.x, py0.x, ss0.x, lbl0.x)
  POSFIX(px0.y, py0.y, ss0.y, lbl0.y)
  POSFIX(px0.z, py0.z, ss0.z, lbl0.z)
  POSFIX(px0.w, py0.w, ss0.w, lbl0.w)
  POSFIX(px1.x, py1.x, ss1.x, lbl1.x)
  POSFIX(px1.y, py1.y, ss1.y, lbl1.y)
  POSFIX(px1.z, py1.z, ss1.z, lbl1.z)
  POSFIX(px1.w, py1.w, ss1.w, lbl1.w)
#undef POSFIX
  #pragma unroll 4
  for (int n = 1; n <= NI; ++n) {
    float4 C = consS[n];
    // branchless: clamp to last bin; far items land at e~2e-7, processed
    // last in the descending scan where p==P already -> contribution ~0.
#define ITEM(P0, P1, SV)                                               \
    {                                                                  \
      float bf = fmaf(C.x, SV, fmaf(C.y, P0, fmaf(C.z, P1, C.w)));     \
      int ib = min((int)bf, NB - 1);                                   \
      atomicAdd(&hr[ib << 3], 1u);                                     \
    }
    ITEM(px0.x, py0.x, ss0.x)
    ITEM(px0.y, py0.y, ss0.y)
    ITEM(px0.z, py0.z, ss0.z)
    ITEM(px0.w, py0.w, ss0.w)
    ITEM(px1.x, py1.x, ss1.x)
    ITEM(px1.y, py1.y, ss1.y)
    ITEM(px1.z, py1.z, ss1.z)
    ITEM(px1.w, py1.w, ss1.w)
#undef ITEM
  }
  __syncthreads();
  // flush to the sample's global t-hist (device-scope u64 atomics:
  // pre-merges across blocks so the tail reads only 8 KB)
  ull* th = ((ull*)ws) + (size_t)s * NB;
  for (int k = t; k < NB; k += 512) {
    uint4 a = *(uint4*)&hist[k * 8];
    uint4 b = *(uint4*)&hist[k * 8 + 4];
    unsigned v = a.x + a.y + a.z + a.w + b.x + b.y + b.z + b.w;
    if (v) {
      ull add = ((ull)(v >> 16) << 32) | (v & 0xFFFFu);
      atomicAdd(&th[k], add);
    }
  }
  __syncthreads();
  if (t == 0) {
    __threadfence();   // release our (atomic) flush before arrival
    flag = (atomicAdd(wsu + W_CNTB + s * 32, 1u) == 63u);
  }
  __syncthreads();
  if (!flag) return;

  // ================= scan phase (one block per sample) =================
  unsigned* ep = hist;
  unsigned* en = hist + EG;
  for (int k = t; k < 2 * EG; k += 512) hist[k] = 0u;
  float vart = ws[W_VART + s];
  __syncthreads();
  // read global t-hist (atomic reads for cross-XCD coherence), scatter to e-grid
  for (int b = t; b < NB; b += 512) {
    ull v = atomicAdd(&th[b], 0ull);
    unsigned pos = (unsigned)(v >> 32), neg = (unsigned)(v & 0xFFFFFFFFu);
    if (pos | neg) {
      float tc = ((float)b + 0.5f) * (1.0f / BSCALE);
      float ex = __expf(-tc);
      if (pos) {
        float e = 2.0f - 2.0f * ex;
        int k = (int)(e * ESCALE); if (k > EG - 1) k = EG - 1;
        atomicAdd(&ep[k], pos);
      }
      if (neg) {
        float e = 2.0f * ex;
        int k = (int)(e * ESCALE); if (k > EG - 1) k = EG - 1;
        atomicAdd(&en[k], neg);
      }
    }
  }
  __syncthreads();
  const int CH = EG / 512;  // 8
  int j0 = t * CH;
  unsigned np = 0, nn = 0;
  for (int k = 0; k < CH; ++k) {
    int b = EG - 1 - (j0 + k);
    np += ep[b]; nn += en[b];
  }
  ull v = ((ull)np << 32) | (ull)nn;
  ull inc = v;
  for (int o = 1; o < 64; o <<= 1) {
    ull u = __shfl_up(inc, o);
    if (lane >= o) inc += u;
  }
  if (lane == 63) wsum[wid] = inc;
  __syncthreads();
  ull offset = 0, total = 0;
  for (int i = 0; i < 8; ++i) {
    ull xr = wsum[i];
    if (i < wid) offset += xr;
    total += xr;
  }
  ull excl = offset + inc - v;
  float P = (float)(unsigned)(total >> 32);
  unsigned p = (unsigned)(excl >> 32), f = (unsigned)(excl & 0xFFFFFFFFu);
  float jprev = 1.0f - (P - (float)p) / (P + (float)f);
  float contrib = 0.f;
  for (int k = 0; k < CH; ++k) {
    int b = EG - 1 - (j0 + k);
    unsigned ap_ = ep[b], an_ = en[b];
    if (ap_ | an_) {
      p += ap_; f += an_;
      float j = 1.0f - (P - (float)p) / (P + (float)f);
      float e = ((float)b + 0.5f) * (2.0f / EG);
      contrib += e * (j - jprev);
      jprev = j;
    }
  }
  for (int o = 32; o; o >>= 1) contrib += __shfl_down(contrib, o);
  if (lane == 0) red[wid] = contrib;
  __syncthreads();
  if (t == 0) {
    float tot = 0.f;
    for (int i = 0; i < 8; ++i) tot += red[i];
    float loss = tot + vart;
    float* fin = ws + W_FINL;
    atomicExch(&fin[s], loss);
    __threadfence();
    unsigned old = atomicAdd(wsu + W_CNTF, 1u);
    if (old == BNUM - 1) {
      float a = 0.f;
      for (int i = 0; i < BNUM; ++i) a += atomicAdd(&fin[i], 0.0f);
      out[0] = a * (1.0f / BNUM);
    }
  }
}

extern "C" void kernel_launch(void* const* d_in, const int* in_sizes, int n_in,
                              void* d_out, int out_size, void* d_ws, size_t ws_size,
                              hipStream_t stream) {
  const float* emb = (const float*)d_in[0];   // [4,2,512,512]
  const float* sig = (const float*)d_in[1];   // [4,1,512,512]
  const int*   gt  = (const int*)d_in[2];     // [4,1,512,512]
  float* out = (float*)d_out;
  float* ws  = (float*)d_ws;

  init_kernel<<<1, 64, 0, stream>>>(ws);
  dim3 g(64, BNUM);   // 256 blocks = 1 per CU
  fused_kernel<<<g, 512, 0, stream>>>(emb, sig, gt, ws, out);
}

// Round 11
// 115.897 us; speedup vs baseline: 1.2699x; 1.2146x over previous
//
#include <hip/hip_runtime.h>

#define HW    262144      // 512*512
#define BNUM  4
#define NC    33          // labels 0..32
#define NI    32          // instance channels

#define NB     1024       // t-space bins
#define BSCALE 64.0f      // NB / TMAX (TMAX = 16)
#define EG     4096       // e-grid bins in scan
#define ESCALE 2048.0f    // EG / 2.0

typedef unsigned long long ull;

// ws layout in 32-bit words:
//   [0 .. 8192)    t-hist: u64[NB] per sample (sample s at ull index s*NB)
//   [8192..8196)   cntB[s]  K2 hist arrival counters
//   [8196]         cntF     finalize counter
//   [8200..8204)   fin[s]   per-sample losses
//   [8204..8208)   vart[s]  pooled variance term (written by cons_kernel)
//   [8208..8736)   cons float4[s][NC]
//   [8736.. )      partials float[s][128][168]
#define W_CNTB 8192
#define W_CNTF 8196
#define W_FINL 8200
#define W_VART 8204
#define W_CONS 8208
#define W_PART 8736
#define PJ 168            // padded words per block slot (165 used)
#define PS (128 * PJ)     // words per sample

// ---------------- K1: per-instance stats -> deterministic partials.
// Also zeroes t-hist + counters (no separate memset dispatch).
__global__ void __launch_bounds__(256) stats_kernel(
    const float* __restrict__ emb, const float* __restrict__ sig,
    const int* __restrict__ gt, float* __restrict__ ws) {
  int s = blockIdx.y;          // sample
  int j = blockIdx.x;          // 0..127 block within sample
  int t = threadIdx.x;
  int w = t >> 6;
  __shared__ float acc[4][165];   // [wave][f*33+n], f: e0,e1,ss,ss2,cnt
  int bid = s * 128 + j;          // 0..511
  unsigned* wsu = (unsigned*)ws;
  const float* e0p = emb + (size_t)s * 2 * HW;
  const float* e1p = e0p + HW;
  const float* sp  = sig + (size_t)s * HW;
  const int*   gp  = gt  + (size_t)s * HW;
  // prefetch: issue ALL input loads before LDS init so HBM latency hides
  int idx0 = j * 2048 + t * 4;
  int idx1 = idx0 + 1024;
  int4   lb0 = *(const int4*)(gp + idx0);
  int4   lb1 = *(const int4*)(gp + idx1);
  float4 x0  = *(const float4*)(e0p + idx0);
  float4 x1  = *(const float4*)(e0p + idx1);
  float4 y0  = *(const float4*)(e1p + idx0);
  float4 y1  = *(const float4*)(e1p + idx1);
  float4 sg0 = *(const float4*)(sp + idx0);
  float4 sg1 = *(const float4*)(sp + idx1);
  if (t < 16) {
    wsu[bid * 16 + t] = 0u;                  // 512*16 = 8192 words of t-hist
    if (bid == 0) wsu[8192 + t] = 0u;        // counters + fin + vart
  }
  for (int k = t; k < 4 * 165; k += 256) ((float*)acc)[k] = 0.f;
  __syncthreads();
#define ACC(L, X, Y, SG)                                                   \
    if (L > 0) {                                                           \
      atomicAdd(&acc[w][L], X);        atomicAdd(&acc[w][33 + L], Y);      \
      atomicAdd(&acc[w][66 + L], SG);  atomicAdd(&acc[w][99 + L], (SG)*(SG)); \
      atomicAdd(&acc[w][132 + L], 1.0f);                                   \
    }
  ACC(lb0.x, x0.x, y0.x, sg0.x)
  ACC(lb0.y, x0.y, y0.y, sg0.y)
  ACC(lb0.z, x0.z, y0.z, sg0.z)
  ACC(lb0.w, x0.w, y0.w, sg0.w)
  ACC(lb1.x, x1.x, y1.x, sg1.x)
  ACC(lb1.y, x1.y, y1.y, sg1.y)
  ACC(lb1.z, x1.z, y1.z, sg1.z)
  ACC(lb1.w, x1.w, y1.w, sg1.w)
#undef ACC
  __syncthreads();
  if (t < 165) {
    float v = acc[0][t] + acc[1][t] + acc[2][t] + acc[3][t];
    ws[W_PART + s * PS + j * PJ + t] = v;   // plain store, unique slot
  }
}

// ---------------- K1b: reduce partials ONCE per sample -> cons + vart.
// Kernel boundary provides coherence; no fences, deterministic sum order.
__global__ void __launch_bounds__(512) cons_kernel(float* __restrict__ ws) {
  int s = blockIdx.x;
  int t = threadIdx.x;
  int lane = t & 63, wid = t >> 6;
  __shared__ float sums2[2][165];
  __shared__ float sums[165];
  if (t < 330) {
    int r = (t >= 165) ? 1 : 0;
    int c = t - r * 165;
    const float* pp = ws + W_PART + s * PS + (r << 6) * PJ + c;
    float sum = 0.f;
    #pragma unroll 16
    for (int jj = 0; jj < 64; ++jj) sum += pp[jj * PJ];
    sums2[r][c] = sum;
  }
  __syncthreads();
  if (t < 165) sums[t] = sums2[0][t] + sums2[1][t];
  __syncthreads();
  if (t >= 1 && t < NC) {
    float c = sums[132 + t];
    float4 C;
    if (c > 0.f) {
      float inv = 1.0f / c;
      float c0 = sums[t] * inv, c1 = sums[33 + t] * inv, sgm = sums[66 + t] * inv;
      float Q = 0.5f / (sgm * sgm) * BSCALE;
      C.x = Q; C.y = -2.0f * Q * c0; C.z = -2.0f * Q * c1;
      C.w = Q * (c0 * c0 + c1 * c1);
    } else {
      C.x = 0.f; C.y = 0.f; C.z = 0.f; C.w = (float)NB;  // overflows -> skipped
    }
    ((float4*)(ws + W_CONS))[s * NC + t] = C;
  }
  if (wid == 0) {   // pooled variance: vart = S_total * (sum 1/c) / NI
    float S = 0.f, rcp = 0.f;
    if (lane >= 1 && lane < NC) {
      float c = sums[132 + lane];
      if (c > 0.f) {
        float sg = sums[66 + lane] / c;
        S = sums[99 + lane] - c * sg * sg;
        rcp = 1.0f / c;
      }
    }
    for (int o = 32; o; o >>= 1) {
      S   += __shfl_down(S, o);
      rcp += __shfl_down(rcp, o);
    }
    if (lane == 0) ws[W_VART + s] = S * rcp / (float)NI;
  }
}

// ---------------- K2: hist (8 sub-hists, 64 blocks/sample) -> u64 flush;
// last-arriving block per sample scans.
__global__ void __launch_bounds__(512) hist_scan_kernel(
    const float* __restrict__ emb, const int* __restrict__ gt,
    float* __restrict__ ws, float* __restrict__ out) {
  int s  = blockIdx.y;
  int lb = blockIdx.x;           // 0..63
  __shared__ unsigned hist[NB * 8];   // 32 KB; 8 sub-hists, aliased e-grid in tail
  __shared__ float4 cons[NC];
  __shared__ ull wsum[8];
  __shared__ float red[8];
  __shared__ int flag;
  int t = threadIdx.x;
  int lane = t & 63, wid = t >> 6;
  const float* e0p = emb + (size_t)s * 2 * HW;
  const float* e1p = e0p + HW;
  const int*   gp  = gt  + (size_t)s * HW;
  // prefetch: 8 px/thread, all loads issued before LDS init (latency hidden)
  int base = lb * 4096 + t * 4;
  int4   lbl0 = *(const int4*)(gp + base);
  int4   lbl1 = *(const int4*)(gp + base + 2048);
  float4 px0  = *(const float4*)(e0p + base);
  float4 px1  = *(const float4*)(e0p + base + 2048);
  float4 py0  = *(const float4*)(e1p + base);
  float4 py1  = *(const float4*)(e1p + base + 2048);
  for (int k = t; k < NB * 8; k += 512) hist[k] = 0u;
  if (t < NC) cons[t] = ((const float4*)(ws + W_CONS))[s * NC + t];
  float4 ss0, ss1;
  ss0.x = fmaf(px0.x, px0.x, py0.x * py0.x);
  ss0.y = fmaf(px0.y, px0.y, py0.y * py0.y);
  ss0.z = fmaf(px0.z, px0.z, py0.z * py0.z);
  ss0.w = fmaf(px0.w, px0.w, py0.w * py0.w);
  ss1.x = fmaf(px1.x, px1.x, py1.x * py1.x);
  ss1.y = fmaf(px1.y, px1.y, py1.y * py1.y);
  ss1.z = fmaf(px1.z, px1.z, py1.z * py1.z);
  ss1.w = fmaf(px1.w, px1.w, py1.w * py1.w);
  __syncthreads();
  unsigned* hr = hist + (t & 7);
  // pos item: the n-loop adds 1 (neg) only when ib<NB. If the pos item's raw
  // bin fits, add 0xFFFF (total 0x10000 with the loop's +1); if it overflows,
  // the loop will skip it -> add the full 0x10000 at the last bin.
  // (round-0-proven semantics: far NEG items are dropped entirely; their
  // e-weight is ~2e-7 and they sit last in the descending scan.)
#define POSFIX(P0, P1, SV, L)                                            \
    if (L > 0) {                                                         \
      float4 C = cons[L];                                                \
      float bf = fmaf(C.x, SV, fmaf(C.y, P0, fmaf(C.z, P1, C.w)));       \
      int ib = (int)bf;                                                  \
      if (ib < NB) atomicAdd(&hr[ib << 3], 0xFFFFu);                     \
      else         atomicAdd(&hr[(NB - 1) << 3], 0x10000u);              \
    }
  POSFIX(px0.x, py0.x, ss0.x, lbl0.x)
  POSFIX(px0.y, py0.y, ss0.y, lbl0.y)
  POSFIX(px0.z, py0.z, ss0.z, lbl0.z)
  POSFIX(px0.w, py0.w, ss0.w, lbl0.w)
  POSFIX(px1.x, py1.x, ss1.x, lbl1.x)
  POSFIX(px1.y, py1.y, ss1.y, lbl1.y)
  POSFIX(px1.z, py1.z, ss1.z, lbl1.z)
  POSFIX(px1.w, py1.w, ss1.w, lbl1.w)
#undef POSFIX
  #pragma unroll 4
  for (int n = 1; n <= NI; ++n) {
    float4 C = cons[n];
#define ITEM(P0, P1, SV)                                               \
    {                                                                  \
      float bf = fmaf(C.x, SV, fmaf(C.y, P0, fmaf(C.z, P1, C.w)));     \
      int ib = (int)bf;                                                \
      if (ib < NB) atomicAdd(&hr[ib << 3], 1u);                        \
    }
    ITEM(px0.x, py0.x, ss0.x)
    ITEM(px0.y, py0.y, ss0.y)
    ITEM(px0.z, py0.z, ss0.z)
    ITEM(px0.w, py0.w, ss0.w)
    ITEM(px1.x, py1.x, ss1.x)
    ITEM(px1.y, py1.y, ss1.y)
    ITEM(px1.z, py1.z, ss1.z)
    ITEM(px1.w, py1.w, ss1.w)
#undef ITEM
  }
  __syncthreads();
  // flush to the sample's global t-hist (device-scope u64 atomics: this
  // pre-merges across blocks so the tail reads only 8 KB); 64 blocks/sample
  ull* th = ((ull*)ws) + (size_t)s * NB;
  for (int k = t; k < NB; k += 512) {
    uint4 a = *(uint4*)&hist[k * 8];
    uint4 b = *(uint4*)&hist[k * 8 + 4];
    unsigned v = a.x + a.y + a.z + a.w + b.x + b.y + b.z + b.w;
    if (v) {
      ull add = ((ull)(v >> 16) << 32) | (v & 0xFFFFu);
      atomicAdd(&th[k], add);
    }
  }
  __syncthreads();
  if (t == 0) {
    __threadfence();   // release our (atomic) flush before arrival
    flag = (atomicAdd((unsigned*)ws + W_CNTB + s, 1u) == 63u);
  }
  __syncthreads();
  if (!flag) return;

  // ================= scan phase (one block per sample) =================
  unsigned* ep = hist;
  unsigned* en = hist + EG;
  for (int k = t; k < 2 * EG; k += 512) hist[k] = 0u;
  float vart = ws[W_VART + s];
  __syncthreads();
  // read global t-hist (atomic reads for cross-XCD coherence), scatter to e-grid
  for (int b = t; b < NB; b += 512) {
    ull v = atomicAdd(&th[b], 0ull);
    unsigned pos = (unsigned)(v >> 32), neg = (unsigned)(v & 0xFFFFFFFFu);
    if (pos | neg) {
      float tc = ((float)b + 0.5f) * (1.0f / BSCALE);
      float ex = __expf(-tc);
      if (pos) {
        float e = 2.0f - 2.0f * ex;
        int k = (int)(e * ESCALE); if (k > EG - 1) k = EG - 1;
        atomicAdd(&ep[k], pos);
      }
      if (neg) {
        float e = 2.0f * ex;
        int k = (int)(e * ESCALE); if (k > EG - 1) k = EG - 1;
        atomicAdd(&en[k], neg);
      }
    }
  }
  __syncthreads();
  const int CH = EG / 512;  // 8
  int j0 = t * CH;
  unsigned np = 0, nn = 0;
  for (int k = 0; k < CH; ++k) {
    int b = EG - 1 - (j0 + k);
    np += ep[b]; nn += en[b];
  }
  ull v = ((ull)np << 32) | (ull)nn;
  ull inc = v;
  for (int o = 1; o < 64; o <<= 1) {
    ull u = __shfl_up(inc, o);
    if (lane >= o) inc += u;
  }
  if (lane == 63) wsum[wid] = inc;
  __syncthreads();
  ull offset = 0, total = 0;
  for (int i = 0; i < 8; ++i) {
    ull xr = wsum[i];
    if (i < wid) offset += xr;
    total += xr;
  }
  ull excl = offset + inc - v;
  float P = (float)(unsigned)(total >> 32);
  unsigned p = (unsigned)(excl >> 32), f = (unsigned)(excl & 0xFFFFFFFFu);
  float jprev = 1.0f - (P - (float)p) / (P + (float)f);
  float contrib = 0.f;
  for (int k = 0; k < CH; ++k) {
    int b = EG - 1 - (j0 + k);
    unsigned ap_ = ep[b], an_ = en[b];
    if (ap_ | an_) {
      p += ap_; f += an_;
      float j = 1.0f - (P - (float)p) / (P + (float)f);
      float e = ((float)b + 0.5f) * (2.0f / EG);
      contrib += e * (j - jprev);
      jprev = j;
    }
  }
  for (int o = 32; o; o >>= 1) contrib += __shfl_down(contrib, o);
  if (lane == 0) red[wid] = contrib;
  __syncthreads();
  if (t == 0) {
    float tot = 0.f;
    for (int i = 0; i < 8; ++i) tot += red[i];
    float loss = tot + vart;
    float* fin = ws + W_FINL;
    atomicExch(&fin[s], loss);
    __threadfence();
    unsigned old = atomicAdd((unsigned*)ws + W_CNTF, 1u);
    if (old == BNUM - 1) {
      float a = 0.f;
      for (int i = 0; i < BNUM; ++i) a += atomicAdd(&fin[i], 0.0f);
      out[0] = a * (1.0f / BNUM);
    }
  }
}

extern "C" void kernel_launch(void* const* d_in, const int* in_sizes, int n_in,
                              void* d_out, int out_size, void* d_ws, size_t ws_size,
                              hipStream_t stream) {
  const float* emb = (const float*)d_in[0];   // [4,2,512,512]
  const float* sig = (const float*)d_in[1];   // [4,1,512,512]
  const int*   gt  = (const int*)d_in[2];     // [4,1,512,512]
  float* out = (float*)d_out;
  float* ws  = (float*)d_ws;

  dim3 gA(128, BNUM);
  stats_kernel<<<gA, 256, 0, stream>>>(emb, sig, gt, ws);
  cons_kernel<<<BNUM, 512, 0, stream>>>(ws);
  dim3 gB(64, BNUM);
  hist_scan_kernel<<<gB, 512, 0, stream>>>(emb, gt, ws, out);
}